// Round 2
// baseline (16325.827 us; speedup 1.0000x reference)
//
#include <hip/hip_runtime.h>

// LightGCN-style 2-layer propagation, N=100000, D=64, NNZ=1.6M per matrix.
// Round 2: fix dropout bits — JAX partitionable threefry returns XOR of the
// two threefry2x32 output words for 32-bit draws (bits1 ^ bits2), counter =
// 64-bit row-major linear index (hi=0 here since N*D < 2^32).

#define TF_ROUND(x0, x1, r) { x0 += x1; x1 = ((x1 << r) | (x1 >> (32 - r))); x1 ^= x0; }

__host__ __device__ inline void threefry2x32(unsigned k0, unsigned k1,
                                             unsigned& x0, unsigned& x1) {
  unsigned k2 = k0 ^ k1 ^ 0x1BD11BDAu;
  x0 += k0; x1 += k1;
  TF_ROUND(x0, x1, 13) TF_ROUND(x0, x1, 15) TF_ROUND(x0, x1, 26) TF_ROUND(x0, x1, 6)
  x0 += k1; x1 += k2 + 1u;
  TF_ROUND(x0, x1, 17) TF_ROUND(x0, x1, 29) TF_ROUND(x0, x1, 16) TF_ROUND(x0, x1, 24)
  x0 += k2; x1 += k0 + 2u;
  TF_ROUND(x0, x1, 13) TF_ROUND(x0, x1, 15) TF_ROUND(x0, x1, 26) TF_ROUND(x0, x1, 6)
  x0 += k0; x1 += k1 + 3u;
  TF_ROUND(x0, x1, 17) TF_ROUND(x0, x1, 29) TF_ROUND(x0, x1, 16) TF_ROUND(x0, x1, 24)
  x0 += k1; x1 += k2 + 4u;
  TF_ROUND(x0, x1, 13) TF_ROUND(x0, x1, 15) TF_ROUND(x0, x1, 26) TF_ROUND(x0, x1, 6)
  x0 += k2; x1 += k0 + 5u;
}

// D = 64 floats = 16 float4 per row. 16 threads per edge, one float4 each.
__global__ void __launch_bounds__(256) spmm_atomic_kernel(
    const int* __restrict__ rows, const int* __restrict__ cols,
    const float* __restrict__ vals, const float* __restrict__ x,
    float* __restrict__ out, int nnz) {
  long tid = (long)blockIdx.x * blockDim.x + threadIdx.x;
  long edge = tid >> 4;
  int sub = (int)(tid & 15);
  if (edge >= nnz) return;
  int r = rows[edge];
  int c = cols[edge];
  float v = vals[edge];
  float4 xv = reinterpret_cast<const float4*>(x)[(long)c * 16 + sub];
  float* o = out + (long)r * 64 + (long)sub * 4;
  atomicAdd(o + 0, v * xv.x);
  atomicAdd(o + 1, v * xv.y);
  atomicAdd(o + 2, v * xv.z);
  atomicAdd(o + 3, v * xv.w);
}

// e = keep(idx) ? t[idx]/0.9 : 0;  t[idx] = e (feeds next layer);  acc[idx] += e.
__global__ void __launch_bounds__(256) dropout_acc_kernel(
    float* __restrict__ t, float* __restrict__ acc,
    unsigned k0, unsigned k1, int n) {
  int idx = blockIdx.x * blockDim.x + threadIdx.x;
  if (idx >= n) return;
  unsigned x0 = 0u, x1 = (unsigned)idx;   // counter (hi, lo) = (0, linear idx)
  threefry2x32(k0, k1, x0, x1);
  unsigned bits = x0 ^ x1;                // partitionable 32-bit draw = XOR of words
  float u = __uint_as_float(0x3F800000u | (bits >> 9)) - 1.0f;
  float e = (u < 0.9f) ? t[idx] * (1.0f / 0.9f) : 0.0f;
  t[idx] = e;
  acc[idx] += e;
}

__global__ void __launch_bounds__(256) scale4_kernel(float* __restrict__ o, float s, int n4) {
  int i = blockIdx.x * blockDim.x + threadIdx.x;
  if (i >= n4) return;
  float4 v = reinterpret_cast<float4*>(o)[i];
  v.x *= s; v.y *= s; v.z *= s; v.w *= s;
  reinterpret_cast<float4*>(o)[i] = v;
}

extern "C" void kernel_launch(void* const* d_in, const int* in_sizes, int n_in,
                              void* d_out, int out_size, void* d_ws, size_t ws_size,
                              hipStream_t stream) {
  const float* user_emb = (const float*)d_in[0];
  const float* item_emb = (const float*)d_in[1];
  const int*   u1_r = (const int*)d_in[2];
  const int*   u1_c = (const int*)d_in[3];
  const float* u1_v = (const float*)d_in[4];
  const int*   u2_r = (const int*)d_in[5];
  const int*   u2_c = (const int*)d_in[6];
  const float* u2_v = (const float*)d_in[7];
  const int*   i1_r = (const int*)d_in[8];
  const int*   i1_c = (const int*)d_in[9];
  const float* i1_v = (const float*)d_in[10];
  const int*   i2_r = (const int*)d_in[11];
  const int*   i2_c = (const int*)d_in[12];
  const float* i2_v = (const float*)d_in[13];
  const int*   cat_r = (const int*)d_in[14];
  const int*   cat_c = (const int*)d_in[15];
  const float* cat_v = (const float*)d_in[16];

  const int ND = in_sizes[0];      // N * 64
  const int nnz1 = in_sizes[2];    // all adjacency matrices share NNZ
  const int nnzc = in_sizes[16];

  float* out_u = (float*)d_out;
  float* out_i = out_u + ND;
  float* B1 = (float*)d_ws;
  float* B2 = B1 + ND;
  float* B3 = B2 + ND;

  // fold_in(key(50), d) for d = 0..3  (u-layer0, u-layer1, i-layer0, i-layer1)
  unsigned keys[4][2];
  for (unsigned d = 0; d < 4; ++d) {
    unsigned x0 = 0u, x1 = d;
    threefry2x32(0u, 50u, x0, x1);
    keys[d][0] = x0; keys[d][1] = x1;
  }

  auto spmm = [&](const int* r, const int* c, const float* v, int nnz,
                  const float* x, float* o) {
    hipMemsetAsync(o, 0, (size_t)ND * sizeof(float), stream);
    long threads = (long)nnz * 16;
    int grid = (int)((threads + 255) / 256);
    spmm_atomic_kernel<<<grid, 256, 0, stream>>>(r, c, v, x, o, nnz);
  };

  const int dgrid = (ND + 255) / 256;

  // ---------------- user path ----------------
  hipMemcpyAsync(out_u, user_emb, (size_t)ND * sizeof(float),
                 hipMemcpyDeviceToDevice, stream);
  // layer 0: u2 -> u1 -> cat -> dropout(key 0)
  spmm(u2_r, u2_c, u2_v, nnz1, user_emb, B1);
  spmm(u1_r, u1_c, u1_v, nnz1, B1, B2);
  spmm(cat_r, cat_c, cat_v, nnzc, B2, B3);
  dropout_acc_kernel<<<dgrid, 256, 0, stream>>>(B3, out_u, keys[0][0], keys[0][1], ND);
  // layer 1: input = B3
  spmm(u2_r, u2_c, u2_v, nnz1, B3, B1);
  spmm(u1_r, u1_c, u1_v, nnz1, B1, B2);
  spmm(cat_r, cat_c, cat_v, nnzc, B2, B3);
  dropout_acc_kernel<<<dgrid, 256, 0, stream>>>(B3, out_u, keys[1][0], keys[1][1], ND);

  // ---------------- item path ----------------
  hipMemcpyAsync(out_i, item_emb, (size_t)ND * sizeof(float),
                 hipMemcpyDeviceToDevice, stream);
  spmm(i2_r, i2_c, i2_v, nnz1, item_emb, B1);
  spmm(i1_r, i1_c, i1_v, nnz1, B1, B2);
  spmm(cat_r, cat_c, cat_v, nnzc, B2, B3);
  dropout_acc_kernel<<<dgrid, 256, 0, stream>>>(B3, out_i, keys[2][0], keys[2][1], ND);
  spmm(i2_r, i2_c, i2_v, nnz1, B3, B1);
  spmm(i1_r, i1_c, i1_v, nnz1, B1, B2);
  spmm(cat_r, cat_c, cat_v, nnzc, B2, B3);
  dropout_acc_kernel<<<dgrid, 256, 0, stream>>>(B3, out_i, keys[3][0], keys[3][1], ND);

  // mean over 3 embeddings
  const int n4 = (2 * ND) / 4;
  scale4_kernel<<<(n4 + 255) / 256, 256, 0, stream>>>((float*)d_out, 1.0f / 3.0f, n4);
}

// Round 3
// 1705.772 us; speedup vs baseline: 9.5709x; 9.5709x over previous
//
#include <hip/hip_runtime.h>

// LightGCN-style 2-layer propagation, N=100000, D=64, NNZ=1.6M per matrix.
// Round 3: replace atomic COO SpMM (atomic-write-through bound, 1.6GB HBM
// writes per dispatch) with on-device CSR build + gather-reduce SpMM.
// Dropout fused into the cat-SpMM of each layer.

#define TF_ROUND(x0, x1, r) { x0 += x1; x1 = ((x1 << r) | (x1 >> (32 - r))); x1 ^= x0; }

__host__ __device__ inline void threefry2x32(unsigned k0, unsigned k1,
                                             unsigned& x0, unsigned& x1) {
  unsigned k2 = k0 ^ k1 ^ 0x1BD11BDAu;
  x0 += k0; x1 += k1;
  TF_ROUND(x0, x1, 13) TF_ROUND(x0, x1, 15) TF_ROUND(x0, x1, 26) TF_ROUND(x0, x1, 6)
  x0 += k1; x1 += k2 + 1u;
  TF_ROUND(x0, x1, 17) TF_ROUND(x0, x1, 29) TF_ROUND(x0, x1, 16) TF_ROUND(x0, x1, 24)
  x0 += k2; x1 += k0 + 2u;
  TF_ROUND(x0, x1, 13) TF_ROUND(x0, x1, 15) TF_ROUND(x0, x1, 26) TF_ROUND(x0, x1, 6)
  x0 += k0; x1 += k1 + 3u;
  TF_ROUND(x0, x1, 17) TF_ROUND(x0, x1, 29) TF_ROUND(x0, x1, 16) TF_ROUND(x0, x1, 24)
  x0 += k1; x1 += k2 + 4u;
  TF_ROUND(x0, x1, 13) TF_ROUND(x0, x1, 15) TF_ROUND(x0, x1, 26) TF_ROUND(x0, x1, 6)
  x0 += k2; x1 += k0 + 5u;
}

__device__ inline float drop1(float val, unsigned k0, unsigned k1, unsigned idx) {
  unsigned x0 = 0u, x1 = idx;            // counter (hi, lo) = (0, linear idx)
  threefry2x32(k0, k1, x0, x1);
  unsigned bits = x0 ^ x1;               // partitionable 32-bit draw
  float u = __uint_as_float(0x3F800000u | (bits >> 9)) - 1.0f;
  return (u < 0.9f) ? val * (1.0f / 0.9f) : 0.0f;
}

// ---------------- CSR build ----------------

__global__ void __launch_bounds__(256) hist_kernel(
    const int* __restrict__ rows, int* __restrict__ cnt, int nnz) {
  int e = blockIdx.x * 256 + threadIdx.x;
  if (e < nnz) atomicAdd(&cnt[rows[e]], 1);
}

__global__ void __launch_bounds__(256) chunk_sum_kernel(
    const int* __restrict__ cnt, int* __restrict__ chunk_sums, int n) {
  __shared__ int s[256];
  int i = blockIdx.x * 256 + threadIdx.x;
  s[threadIdx.x] = (i < n) ? cnt[i] : 0;
  __syncthreads();
  for (int off = 128; off > 0; off >>= 1) {
    if (threadIdx.x < off) s[threadIdx.x] += s[threadIdx.x + off];
    __syncthreads();
  }
  if (threadIdx.x == 0) chunk_sums[blockIdx.x] = s[0];
}

// exclusive scan of chunk_sums in place; nchunks <= 1024
__global__ void __launch_bounds__(1024) scan_chunks_kernel(
    int* __restrict__ chunk_sums, int nchunks) {
  __shared__ int s[1024];
  int t = threadIdx.x;
  int v = (t < nchunks) ? chunk_sums[t] : 0;
  s[t] = v;
  __syncthreads();
  for (int off = 1; off < 1024; off <<= 1) {
    int x = (t >= off) ? s[t - off] : 0;
    __syncthreads();
    s[t] += x;
    __syncthreads();
  }
  if (t < nchunks) chunk_sums[t] = s[t] - v;   // exclusive
}

__global__ void __launch_bounds__(256) scan_within_kernel(
    const int* __restrict__ cnt, const int* __restrict__ chunk_off,
    int* __restrict__ row_ptr, int n) {
  __shared__ int s[256];
  int t = threadIdx.x;
  int i = blockIdx.x * 256 + t;
  int v = (i < n) ? cnt[i] : 0;
  s[t] = v;
  __syncthreads();
  for (int off = 1; off < 256; off <<= 1) {
    int x = (t >= off) ? s[t - off] : 0;
    __syncthreads();
    s[t] += x;
    __syncthreads();
  }
  int base = chunk_off[blockIdx.x];
  if (i < n)      row_ptr[i] = base + s[t] - v;  // exclusive
  if (i == n - 1) row_ptr[n] = base + s[t];      // total = nnz
}

__global__ void __launch_bounds__(256) scatter_kernel(
    const int* __restrict__ rows, const int* __restrict__ cols,
    const float* __restrict__ vals, const int* __restrict__ row_ptr,
    int* __restrict__ fill, int2* __restrict__ pairs, int nnz) {
  int e = blockIdx.x * 256 + threadIdx.x;
  if (e >= nnz) return;
  int r = rows[e];
  int pos = row_ptr[r] + atomicAdd(&fill[r], 1);
  pairs[pos] = make_int2(cols[e], __float_as_int(vals[e]));
}

// ---------------- CSR SpMM ----------------
// 16 threads per row; thread `sub` owns float4 slice `sub` of D=64.

__global__ void __launch_bounds__(256) spmm_csr_kernel(
    const int* __restrict__ row_ptr, const int2* __restrict__ pairs,
    const float* __restrict__ x, float* __restrict__ out, int N) {
  int tid = blockIdx.x * 256 + threadIdx.x;
  int row = tid >> 4, sub = tid & 15;
  if (row >= N) return;
  int s = row_ptr[row], e = row_ptr[row + 1];
  const float4* x4 = reinterpret_cast<const float4*>(x);
  float4 acc = {0.f, 0.f, 0.f, 0.f};
  for (int i = s; i < e; ++i) {
    int2 p = pairs[i];
    float v = __int_as_float(p.y);
    float4 xv = x4[(size_t)p.x * 16 + sub];
    acc.x += v * xv.x; acc.y += v * xv.y; acc.z += v * xv.z; acc.w += v * xv.w;
  }
  reinterpret_cast<float4*>(out)[(size_t)row * 16 + sub] = acc;
}

// cat-SpMM + dropout + accumulate-into-output, fused.
__global__ void __launch_bounds__(256) spmm_csr_drop_kernel(
    const int* __restrict__ row_ptr, const int2* __restrict__ pairs,
    const float* __restrict__ x, float* __restrict__ t_out,
    float* __restrict__ accb, unsigned k0, unsigned k1, int N) {
  int tid = blockIdx.x * 256 + threadIdx.x;
  int row = tid >> 4, sub = tid & 15;
  if (row >= N) return;
  int s = row_ptr[row], e = row_ptr[row + 1];
  const float4* x4 = reinterpret_cast<const float4*>(x);
  float4 acc = {0.f, 0.f, 0.f, 0.f};
  for (int i = s; i < e; ++i) {
    int2 p = pairs[i];
    float v = __int_as_float(p.y);
    float4 xv = x4[(size_t)p.x * 16 + sub];
    acc.x += v * xv.x; acc.y += v * xv.y; acc.z += v * xv.z; acc.w += v * xv.w;
  }
  unsigned base = (unsigned)row * 64u + (unsigned)sub * 4u;
  float4 t;
  t.x = drop1(acc.x, k0, k1, base + 0u);
  t.y = drop1(acc.y, k0, k1, base + 1u);
  t.z = drop1(acc.z, k0, k1, base + 2u);
  t.w = drop1(acc.w, k0, k1, base + 3u);
  size_t o = (size_t)row * 16 + sub;
  reinterpret_cast<float4*>(t_out)[o] = t;
  float4 a = reinterpret_cast<float4*>(accb)[o];
  a.x += t.x; a.y += t.y; a.z += t.z; a.w += t.w;
  reinterpret_cast<float4*>(accb)[o] = a;
}

__global__ void __launch_bounds__(256) scale4_kernel(float* __restrict__ o, float s, int n4) {
  int i = blockIdx.x * 256 + threadIdx.x;
  if (i >= n4) return;
  float4 v = reinterpret_cast<float4*>(o)[i];
  v.x *= s; v.y *= s; v.z *= s; v.w *= s;
  reinterpret_cast<float4*>(o)[i] = v;
}

// ---------------- fallback (R2 atomic path) ----------------

__global__ void __launch_bounds__(256) spmm_atomic_kernel(
    const int* __restrict__ rows, const int* __restrict__ cols,
    const float* __restrict__ vals, const float* __restrict__ x,
    float* __restrict__ out, int nnz) {
  long tid = (long)blockIdx.x * blockDim.x + threadIdx.x;
  long edge = tid >> 4;
  int sub = (int)(tid & 15);
  if (edge >= nnz) return;
  int r = rows[edge];
  int c = cols[edge];
  float v = vals[edge];
  float4 xv = reinterpret_cast<const float4*>(x)[(long)c * 16 + sub];
  float* o = out + (long)r * 64 + (long)sub * 4;
  atomicAdd(o + 0, v * xv.x);
  atomicAdd(o + 1, v * xv.y);
  atomicAdd(o + 2, v * xv.z);
  atomicAdd(o + 3, v * xv.w);
}

__global__ void __launch_bounds__(256) dropout_acc_kernel(
    float* __restrict__ t, float* __restrict__ acc,
    unsigned k0, unsigned k1, int n) {
  int idx = blockIdx.x * blockDim.x + threadIdx.x;
  if (idx >= n) return;
  float e = drop1(t[idx], k0, k1, (unsigned)idx);
  t[idx] = e;
  acc[idx] += e;
}

// ---------------- launcher ----------------

struct Coo { const int* r; const int* c; const float* v; int nnz; };

extern "C" void kernel_launch(void* const* d_in, const int* in_sizes, int n_in,
                              void* d_out, int out_size, void* d_ws, size_t ws_size,
                              hipStream_t stream) {
  const float* user_emb = (const float*)d_in[0];
  const float* item_emb = (const float*)d_in[1];
  enum { U1 = 0, U2 = 1, I1 = 2, I2 = 3, CAT = 4 };
  Coo mats[5] = {
    { (const int*)d_in[2],  (const int*)d_in[3],  (const float*)d_in[4],  in_sizes[2]  },
    { (const int*)d_in[5],  (const int*)d_in[6],  (const float*)d_in[7],  in_sizes[5]  },
    { (const int*)d_in[8],  (const int*)d_in[9],  (const float*)d_in[10], in_sizes[8]  },
    { (const int*)d_in[11], (const int*)d_in[12], (const float*)d_in[13], in_sizes[11] },
    { (const int*)d_in[14], (const int*)d_in[15], (const float*)d_in[16], in_sizes[14] },
  };

  const int ND = in_sizes[0];     // N * 64
  const int N = ND / 64;
  const int nchunks = (N + 255) / 256;   // <= 1024 required (N <= 262144)

  float* out_u = (float*)d_out;
  float* out_i = out_u + ND;

  // fold_in(key(50), d), d = tag*L+li for (u,L0),(u,L1),(i,L0),(i,L1)
  unsigned keys[4][2];
  for (unsigned d = 0; d < 4; ++d) {
    unsigned x0 = 0u, x1 = d;
    threefry2x32(0u, 50u, x0, x1);
    keys[d][0] = x0; keys[d][1] = x1;
  }

  size_t maxnnz = 0, sum_pairs = 0;
  for (int m = 0; m < 5; ++m) {
    size_t b = ((size_t)mats[m].nnz * 8 + 255) & ~255ULL;
    sum_pairs += b;
    if ((size_t)mats[m].nnz > maxnnz) maxnnz = (size_t)mats[m].nnz;
  }
  auto AL = [](size_t b) { return (b + 255) & ~255ULL; };
  const size_t need_common = 2 * AL((size_t)ND * 4) + 2 * AL((size_t)N * 4) + AL(4096);
  const size_t need_big   = need_common + 5 * AL((size_t)(N + 1) * 4) + sum_pairs;
  const size_t need_small = need_common + AL((size_t)(N + 1) * 4) + AL(maxnnz * 8);

  int mode = (ws_size >= need_big) ? 2 : (ws_size >= need_small) ? 1 : 0;

  if (mode == 0) {
    // -------- atomic fallback (R2) --------
    float* B1 = (float*)d_ws;
    float* B2 = B1 + ND;
    float* B3 = B2 + ND;
    auto spmm = [&](const Coo& m, const float* x, float* o) {
      hipMemsetAsync(o, 0, (size_t)ND * sizeof(float), stream);
      long threads = (long)m.nnz * 16;
      spmm_atomic_kernel<<<(int)((threads + 255) / 256), 256, 0, stream>>>(
          m.r, m.c, m.v, x, o, m.nnz);
    };
    const int dgrid = (ND + 255) / 256;
    for (int path = 0; path < 2; ++path) {
      const float* h0 = path ? item_emb : user_emb;
      float* acc = path ? out_i : out_u;
      const Coo& A2 = mats[path ? I2 : U2];
      const Coo& A1 = mats[path ? I1 : U1];
      hipMemcpyAsync(acc, h0, (size_t)ND * sizeof(float), hipMemcpyDeviceToDevice, stream);
      const float* in = h0;
      for (int li = 0; li < 2; ++li) {
        spmm(A2, in, B1);
        spmm(A1, B1, B2);
        spmm(mats[CAT], B2, B3);
        int d = path * 2 + li;
        dropout_acc_kernel<<<dgrid, 256, 0, stream>>>(B3, acc, keys[d][0], keys[d][1], ND);
        in = B3;
      }
    }
    const int n4 = (2 * ND) / 4;
    scale4_kernel<<<(n4 + 255) / 256, 256, 0, stream>>>((float*)d_out, 1.0f / 3.0f, n4);
    return;
  }

  // -------- CSR path --------
  char* p = (char*)d_ws;
  auto take = [&](size_t bytes) { char* q = p; p += (bytes + 255) & ~255ULL; return (void*)q; };
  float* B1 = (float*)take((size_t)ND * 4);
  float* B2 = (float*)take((size_t)ND * 4);
  int* cnt  = (int*)take((size_t)N * 4);
  int* fill = (int*)take((size_t)N * 4);
  int* chunk_sums = (int*)take(4096);
  int* rp[5]; int2* prs[5];
  if (mode == 2) {
    for (int m = 0; m < 5; ++m) rp[m] = (int*)take((size_t)(N + 1) * 4);
    for (int m = 0; m < 5; ++m) prs[m] = (int2*)take((size_t)mats[m].nnz * 8);
  } else {
    rp[0] = (int*)take((size_t)(N + 1) * 4);
    prs[0] = (int2*)take(maxnnz * 8);
  }

  auto build_csr = [&](const Coo& m, int* rowp, int2* pairs) {
    hipMemsetAsync(cnt, 0, (size_t)N * 4, stream);
    int egrid = (m.nnz + 255) / 256;
    hist_kernel<<<egrid, 256, 0, stream>>>(m.r, cnt, m.nnz);
    chunk_sum_kernel<<<nchunks, 256, 0, stream>>>(cnt, chunk_sums, N);
    scan_chunks_kernel<<<1, 1024, 0, stream>>>(chunk_sums, nchunks);
    scan_within_kernel<<<nchunks, 256, 0, stream>>>(cnt, chunk_sums, rowp, N);
    hipMemsetAsync(fill, 0, (size_t)N * 4, stream);
    scatter_kernel<<<egrid, 256, 0, stream>>>(m.r, m.c, m.v, rowp, fill, pairs, m.nnz);
  };

  if (mode == 2)
    for (int m = 0; m < 5; ++m) build_csr(mats[m], rp[m], prs[m]);

  const int sgrid = (N * 16 + 255) / 256;

  auto spmm_plain = [&](int mi, const float* x, float* o) {
    int* rowp; int2* pairs;
    if (mode == 2) { rowp = rp[mi]; pairs = prs[mi]; }
    else { build_csr(mats[mi], rp[0], prs[0]); rowp = rp[0]; pairs = prs[0]; }
    spmm_csr_kernel<<<sgrid, 256, 0, stream>>>(rowp, pairs, x, o, N);
  };
  auto spmm_drop = [&](int mi, const float* x, float* t, float* accb, int d) {
    int* rowp; int2* pairs;
    if (mode == 2) { rowp = rp[mi]; pairs = prs[mi]; }
    else { build_csr(mats[mi], rp[0], prs[0]); rowp = rp[0]; pairs = prs[0]; }
    spmm_csr_drop_kernel<<<sgrid, 256, 0, stream>>>(rowp, pairs, x, t, accb,
                                                    keys[d][0], keys[d][1], N);
  };

  for (int path = 0; path < 2; ++path) {
    const float* h0 = path ? item_emb : user_emb;
    float* acc = path ? out_i : out_u;
    int A2 = path ? I2 : U2;
    int A1 = path ? I1 : U1;
    hipMemcpyAsync(acc, h0, (size_t)ND * sizeof(float), hipMemcpyDeviceToDevice, stream);
    // layer 0
    spmm_plain(A2, h0, B1);
    spmm_plain(A1, B1, B2);
    spmm_drop(CAT, B2, B1, acc, path * 2 + 0);   // t -> B1
    // layer 1
    spmm_plain(A2, B1, B2);
    spmm_plain(A1, B2, B1);
    spmm_drop(CAT, B1, B2, acc, path * 2 + 1);   // t -> B2 (unused after)
  }

  const int n4 = (2 * ND) / 4;
  scale4_kernel<<<(n4 + 255) / 256, 256, 0, stream>>>((float*)d_out, 1.0f / 3.0f, n4);
}